// Round 9
// baseline (2212.526 us; speedup 1.0000x reference)
//
#include <hip/hip_runtime.h>
#include <stdint.h>

// RNNTextClassifier: B=64, S=512, E=H=512, NCLS=8
// Round 12: asymmetric per-layer step shapes + deeper ring.
//  - Layer1: MERGED single poll {in0[s], h1[s-1]} (R6 shape) -> stage both
//    -> BAR -> 32 MFMAs -> s_part -> BAR -> finals. Layer1 lags layer0, so
//    in0 is always-ready; R8/R11's split poll wasted one serial MALL RT
//    per step on L1's chain. 2 barriers, 1 RT.
//  - Layer0: keeps R11 shape (stage emb -> BAR -> in0 MFMAs -> prefetch ->
//    h-poll(+bp) -> stage H -> BAR -> H MFMAs -> s_part -> BAR -> finals).
//  - Ring 4 -> 8 slots, tag 3 -> 4 bits (lo mask 0xFFF0): bp gate moves to
//    s-8, decoupling layer0 from layer1 jitter. Slot/tag safety: s vs s-8
//    tags differ mod 16; bp-word overwrite excluded by in0 dependency.
//  - Raw LDS-only barriers (R11), fast_tanh (R6), self-contained polls.
// Ring: hsl[layer][slot=s&7][row 0..63][col 0..511] u32; tag = s&15.
// ws: hsl 2MB at offset 0 (memset to 0 each launch).

#define BB 64
#define SS 512
#define HH 512

typedef short bf16x8 __attribute__((ext_vector_type(8)));
typedef float f32x4 __attribute__((ext_vector_type(4)));
typedef int i32x4 __attribute__((ext_vector_type(4)));
typedef unsigned int u32;
typedef u32 u32x2 __attribute__((ext_vector_type(2)));

__device__ __forceinline__ unsigned short f2bf(float f) {
  uint32_t u = __builtin_bit_cast(uint32_t, f);
  u += 0x7FFFu + ((u >> 16) & 1u);
  return (unsigned short)(u >> 16);
}
__device__ __forceinline__ float bf2f(unsigned short h) {
  uint32_t u = ((uint32_t)h) << 16;
  return __builtin_bit_cast(float, u);
}
__device__ __forceinline__ int pack2(unsigned short a, unsigned short b) {
  return (int)(unsigned int)a | ((int)(unsigned int)b << 16);
}
// pack hi halves of two tagged words (a -> low bf16, b -> high bf16)
__device__ __forceinline__ u32 hipack(u32 a, u32 b) {
  return (a >> 16) | (b & 0xFFFF0000u);
}
// pack lo halves (4 tag bits stripped)
__device__ __forceinline__ u32 lopack(u32 a, u32 b) {
  return (a & 0xFFF0u) | ((b & 0xFFF0u) << 16);
}
__device__ __forceinline__ bool tag4(i32x4 v, u32 t) {
  u32 m = (((u32)v[0] ^ t) | ((u32)v[1] ^ t) | ((u32)v[2] ^ t) | ((u32)v[3] ^ t)) & 15u;
  return m == 0u;
}
// fast tanh: t = sign(v)*(1-e)/(1+e), e = exp(-2|v|). |err| ~1e-7.
__device__ __forceinline__ float fast_tanh(float v) {
  float a = __builtin_fabsf(v);
  float e = __expf(-2.0f * a);
  float t = (1.0f - e) / (1.0f + e);
  return __builtin_copysignf(t, v);
}

// LDS-only barrier: no vmcnt drain (barriers protect LDS staging only).
#define BAR_LDS()                                            \
  do {                                                       \
    asm volatile("s_waitcnt lgkmcnt(0)" ::: "memory");       \
    __builtin_amdgcn_s_barrier();                            \
  } while (0)

// device-coherent (UC) loads/stores: bypass non-common caches
#define UC_LOAD4(dst, ptr) \
  asm volatile("global_load_dwordx4 %0, %1, off sc0 sc1" : "=v"(dst) : "v"(ptr))
#define UC_LOAD1(dst, ptr) \
  asm volatile("global_load_dword %0, %1, off sc0 sc1" : "=v"(dst) : "v"(ptr))
#define UC_STORE2(ptr, v) \
  asm volatile("global_store_dwordx2 %0, %1, off sc0 sc1" ::"v"(ptr), "v"(v) : "memory")

__global__ __launch_bounds__(512, 2) void k_rnn(
    const int* __restrict__ x, const float* __restrict__ emb,
    const float* __restrict__ Wih0, const float* __restrict__ Whh0,
    const float* __restrict__ bih0, const float* __restrict__ bhh0,
    const float* __restrict__ Wih1, const float* __restrict__ Whh1,
    const float* __restrict__ bih1, const float* __restrict__ bhh1,
    u32* __restrict__ hsl) {
  const int tid = threadIdx.x;
  const int bid = blockIdx.x;
  const int layer = bid >> 5;  // 0 or 1
  const int lb = bid & 31;
  const int bg = lb >> 3;  // batch group (16 rows)
  const int c = lb & 7;    // hidden slice (64 dims)
  const int wid = tid >> 6;
  const int lane = tid & 63;
  const int kq = wid >> 1;  // K-quarter
  const int nh = wid & 1;   // N-half (32 cols)
  const int r16 = lane & 15, kg = lane >> 4;

  __shared__ __align__(16) unsigned short s_in0[16 * 512];
  __shared__ __align__(16) unsigned short s_Hhi[16 * 512];
  __shared__ __align__(16) unsigned short s_Hlo[16 * 512];
  __shared__ __align__(16) float s_part[4 * 16 * 64];

  const float* Wih = layer ? Wih1 : Wih0;
  const float* Whh = layer ? Whh1 : Whh0;
  const float* bi = layer ? bih1 : bih0;
  const float* bh = layer ? bhh1 : bhh0;

  // ---- one-time: W fragments into VGPRs ----
  bf16x8 wih[2][4], whhh[2][4], whhl[2][4];
  {
#pragma unroll
    for (int nt = 0; nt < 2; ++nt) {
#pragma unroll
      for (int kt = 0; kt < 4; ++kt) {
        int row = c * 64 + nh * 32 + nt * 16 + r16;
        int k0 = kq * 128 + kt * 32 + kg * 8;
        const float* p = Wih + row * 512 + k0;
        bf16x8 v;
#pragma unroll
        for (int j = 0; j < 8; ++j) v[j] = (short)f2bf(p[j]);
        wih[nt][kt] = v;
        const float* q = Whh + row * 512 + k0;
        bf16x8 vh, vl;
#pragma unroll
        for (int j = 0; j < 8; ++j) {
          float f = q[j];
          unsigned short h = f2bf(f);
          vh[j] = (short)h;
          vl[j] = (short)f2bf(f - bf2f(h));
        }
        whhh[nt][kt] = vh;
        whhl[nt][kt] = vl;
      }
    }
  }
  float biasv0, biasv1;
  {
    int na = (tid & 31) * 2;
    biasv0 = bi[c * 64 + na] + bh[c * 64 + na];
    biasv1 = bi[c * 64 + na + 1] + bh[c * 64 + na + 1];
  }

  const int r_st = tid >> 5;  // staging row 0..15
  const int ch = tid & 31;    // 16-element chunk of 512

  // prefetch in0 for step 1 (layer0: emb gather t=0)
  float4 pf0, pf1, pf2, pf3;
  if (layer == 0) {
    int rid = x[(bg * 16 + r_st) * SS + 0];
    const float4* ep = (const float4*)(emb + (size_t)rid * 512 + ch * 16);
    pf0 = ep[0]; pf1 = ep[1]; pf2 = ep[2]; pf3 = ep[3];
  }

  for (int s = 1; s <= SS; ++s) {
    const u32 exp_h = (u32)((s - 1) & 15);
    const u32* ph = hsl +
        (((size_t)layer * 8 + ((s - 1) & 7)) * 64 + bg * 16 + r_st) * 512 + ch * 16;

    f32x4 a0i = {0.f, 0.f, 0.f, 0.f}, a1i = {0.f, 0.f, 0.f, 0.f};
    f32x4 a0hh = {0.f, 0.f, 0.f, 0.f}, a0hl = {0.f, 0.f, 0.f, 0.f},
          a0lh = {0.f, 0.f, 0.f, 0.f};
    f32x4 a1hh = {0.f, 0.f, 0.f, 0.f}, a1hl = {0.f, 0.f, 0.f, 0.f},
          a1lh = {0.f, 0.f, 0.f, 0.f};

    if (layer == 0) {
      // next emb row index (plain load; survives raw barrier un-drained)
      int nrid = 0;
      if (s < SS) nrid = x[(bg * 16 + r_st) * SS + s];

      // ---- stage in0 from prefetched emb f32 (swizzled LDS) ----
      i32x4 v0, v1;
      v0[0] = pack2(f2bf(pf0.x), f2bf(pf0.y));
      v0[1] = pack2(f2bf(pf0.z), f2bf(pf0.w));
      v0[2] = pack2(f2bf(pf1.x), f2bf(pf1.y));
      v0[3] = pack2(f2bf(pf1.z), f2bf(pf1.w));
      v1[0] = pack2(f2bf(pf2.x), f2bf(pf2.y));
      v1[1] = pack2(f2bf(pf2.z), f2bf(pf2.w));
      v1[2] = pack2(f2bf(pf3.x), f2bf(pf3.y));
      v1[3] = pack2(f2bf(pf3.z), f2bf(pf3.w));
      *(i32x4*)(s_in0 + r_st * 512 + (((2 * ch) ^ (r_st & 7)) << 3)) = v0;
      *(i32x4*)(s_in0 + r_st * 512 + (((2 * ch + 1) ^ (r_st & 7)) << 3)) = v1;
      BAR_LDS();  // B1: s_in0 staged

      // ---- in0 MFMAs (h-independent) ----
#pragma unroll
      for (int kt = 0; kt < 4; ++kt) {
        int k8 = kq * 16 + kt * 4 + kg;
        bf16x8 ain = __builtin_bit_cast(
            bf16x8, *(const i32x4*)(s_in0 + r16 * 512 + ((k8 ^ (r16 & 7)) << 3)));
        a0i = __builtin_amdgcn_mfma_f32_16x16x32_bf16(ain, wih[0][kt], a0i, 0, 0, 0);
        a1i = __builtin_amdgcn_mfma_f32_16x16x32_bf16(ain, wih[1][kt], a1i, 0, 0, 0);
      }

      // ---- issue emb prefetch for s+1 (hides under the H-poll RT) ----
      if (s < SS) {
        const float4* ep = (const float4*)(emb + (size_t)nrid * 512 + ch * 16);
        pf0 = ep[0]; pf1 = ep[1]; pf2 = ep[2]; pf3 = ep[3];
      }

      // ---- H poll (self-contained, + bp at s-8) + stage ----
      if (s > 1) {
        i32x4 h0 = {0, 0, 0, 0}, h1 = {0, 0, 0, 0}, h2 = {0, 0, 0, 0},
              h3 = {0, 0, 0, 0};
        const bool need_bp = (s > 8) && (tid < 8);
        const u32 exp_bp = (u32)((s - 8) & 15);
        const u32* pbp = hsl + ((size_t)(8 + ((s - 8) & 7)) * 64 + bg * 16) * 512 +
                         (tid < 8 ? tid * 64 : 0);
        while (true) {
          u32 bpw = 0;
          UC_LOAD4(h0, ph);
          UC_LOAD4(h1, ph + 4);
          UC_LOAD4(h2, ph + 8);
          UC_LOAD4(h3, ph + 12);
          UC_LOAD1(bpw, pbp);
          asm volatile("s_waitcnt vmcnt(0)"
                       : "+v"(h0), "+v"(h1), "+v"(h2), "+v"(h3), "+v"(bpw)::"memory");
          bool ok = tag4(h0, exp_h) && tag4(h1, exp_h) && tag4(h2, exp_h) &&
                    tag4(h3, exp_h) && (!need_bp || ((bpw & 15u) == exp_bp));
          if (__all(ok)) break;
        }
        i32x4 A0 = {(int)hipack(h0[0], h0[1]), (int)hipack(h0[2], h0[3]),
                    (int)hipack(h1[0], h1[1]), (int)hipack(h1[2], h1[3])};
        i32x4 A1 = {(int)hipack(h2[0], h2[1]), (int)hipack(h2[2], h2[3]),
                    (int)hipack(h3[0], h3[1]), (int)hipack(h3[2], h3[3])};
        i32x4 B0 = {(int)lopack(h0[0], h0[1]), (int)lopack(h0[2], h0[3]),
                    (int)lopack(h1[0], h1[1]), (int)lopack(h1[2], h1[3])};
        i32x4 B1v = {(int)lopack(h2[0], h2[1]), (int)lopack(h2[2], h2[3]),
                     (int)lopack(h3[0], h3[1]), (int)lopack(h3[2], h3[3])};
        *(i32x4*)(s_Hhi + r_st * 512 + (((2 * ch) ^ (r_st & 7)) << 3)) = A0;
        *(i32x4*)(s_Hhi + r_st * 512 + (((2 * ch + 1) ^ (r_st & 7)) << 3)) = A1;
        *(i32x4*)(s_Hlo + r_st * 512 + (((2 * ch) ^ (r_st & 7)) << 3)) = B0;
        *(i32x4*)(s_Hlo + r_st * 512 + (((2 * ch + 1) ^ (r_st & 7)) << 3)) = B1v;
      }
      BAR_LDS();  // B2: s_H staged
    } else {
      // ================= layer1: MERGED poll {in0[s], h[s-1]} =============
      i32x4 i0 = {0, 0, 0, 0}, i1 = {0, 0, 0, 0}, i2 = {0, 0, 0, 0},
            i3 = {0, 0, 0, 0};
      i32x4 h0 = {0, 0, 0, 0}, h1 = {0, 0, 0, 0}, h2 = {0, 0, 0, 0},
            h3 = {0, 0, 0, 0};
      const u32 exp_i = (u32)(s & 15);
      const u32* pi =
          hsl + (((size_t)(s & 7)) * 64 + bg * 16 + r_st) * 512 + ch * 16;
      const bool need_h = (s > 1);
      while (true) {
        UC_LOAD4(i0, pi);
        UC_LOAD4(i1, pi + 4);
        UC_LOAD4(i2, pi + 8);
        UC_LOAD4(i3, pi + 12);
        UC_LOAD4(h0, ph);
        UC_LOAD4(h1, ph + 4);
        UC_LOAD4(h2, ph + 8);
        UC_LOAD4(h3, ph + 12);
        asm volatile("s_waitcnt vmcnt(0)"
                     : "+v"(i0), "+v"(i1), "+v"(i2), "+v"(i3), "+v"(h0), "+v"(h1),
                       "+v"(h2), "+v"(h3)::"memory");
        bool ok = tag4(i0, exp_i) && tag4(i1, exp_i) && tag4(i2, exp_i) &&
                  tag4(i3, exp_i) &&
                  (!need_h || (tag4(h0, exp_h) && tag4(h1, exp_h) &&
                               tag4(h2, exp_h) && tag4(h3, exp_h)));
        if (__all(ok)) break;
      }
      // stage in0 (hi halves) + H hi/lo
      i32x4 A0 = {(int)hipack(i0[0], i0[1]), (int)hipack(i0[2], i0[3]),
                  (int)hipack(i1[0], i1[1]), (int)hipack(i1[2], i1[3])};
      i32x4 A1 = {(int)hipack(i2[0], i2[1]), (int)hipack(i2[2], i2[3]),
                  (int)hipack(i3[0], i3[1]), (int)hipack(i3[2], i3[3])};
      *(i32x4*)(s_in0 + r_st * 512 + (((2 * ch) ^ (r_st & 7)) << 3)) = A0;
      *(i32x4*)(s_in0 + r_st * 512 + (((2 * ch + 1) ^ (r_st & 7)) << 3)) = A1;
      if (s > 1) {
        i32x4 C0 = {(int)hipack(h0[0], h0[1]), (int)hipack(h0[2], h0[3]),
                    (int)hipack(h1[0], h1[1]), (int)hipack(h1[2], h1[3])};
        i32x4 C1 = {(int)hipack(h2[0], h2[1]), (int)hipack(h2[2], h2[3]),
                    (int)hipack(h3[0], h3[1]), (int)hipack(h3[2], h3[3])};
        i32x4 D0 = {(int)lopack(h0[0], h0[1]), (int)lopack(h0[2], h0[3]),
                    (int)lopack(h1[0], h1[1]), (int)lopack(h1[2], h1[3])};
        i32x4 D1 = {(int)lopack(h2[0], h2[1]), (int)lopack(h2[2], h2[3]),
                    (int)lopack(h3[0], h3[1]), (int)lopack(h3[2], h3[3])};
        *(i32x4*)(s_Hhi + r_st * 512 + (((2 * ch) ^ (r_st & 7)) << 3)) = C0;
        *(i32x4*)(s_Hhi + r_st * 512 + (((2 * ch + 1) ^ (r_st & 7)) << 3)) = C1;
        *(i32x4*)(s_Hlo + r_st * 512 + (((2 * ch) ^ (r_st & 7)) << 3)) = D0;
        *(i32x4*)(s_Hlo + r_st * 512 + (((2 * ch + 1) ^ (r_st & 7)) << 3)) = D1;
      }
      BAR_LDS();  // B1: s_in0 + s_H staged

      // ---- all 32 MFMAs in one region ----
#pragma unroll
      for (int kt = 0; kt < 4; ++kt) {
        int k8 = kq * 16 + kt * 4 + kg;
        bf16x8 ain = __builtin_bit_cast(
            bf16x8, *(const i32x4*)(s_in0 + r16 * 512 + ((k8 ^ (r16 & 7)) << 3)));
        a0i = __builtin_amdgcn_mfma_f32_16x16x32_bf16(ain, wih[0][kt], a0i, 0, 0, 0);
        a1i = __builtin_amdgcn_mfma_f32_16x16x32_bf16(ain, wih[1][kt], a1i, 0, 0, 0);
      }
      if (s > 1) {
#pragma unroll
        for (int kt = 0; kt < 4; ++kt) {
          int k8 = kq * 16 + kt * 4 + kg;
          bf16x8 ahi = __builtin_bit_cast(
              bf16x8, *(const i32x4*)(s_Hhi + r16 * 512 + ((k8 ^ (r16 & 7)) << 3)));
          bf16x8 alo = __builtin_bit_cast(
              bf16x8, *(const i32x4*)(s_Hlo + r16 * 512 + ((k8 ^ (r16 & 7)) << 3)));
          a0hh = __builtin_amdgcn_mfma_f32_16x16x32_bf16(ahi, whhh[0][kt], a0hh, 0, 0, 0);
          a0hl = __builtin_amdgcn_mfma_f32_16x16x32_bf16(ahi, whhl[0][kt], a0hl, 0, 0, 0);
          a0lh = __builtin_amdgcn_mfma_f32_16x16x32_bf16(alo, whhh[0][kt], a0lh, 0, 0, 0);
          a1hh = __builtin_amdgcn_mfma_f32_16x16x32_bf16(ahi, whhh[1][kt], a1hh, 0, 0, 0);
          a1hl = __builtin_amdgcn_mfma_f32_16x16x32_bf16(ahi, whhl[1][kt], a1hl, 0, 0, 0);
          a1lh = __builtin_amdgcn_mfma_f32_16x16x32_bf16(alo, whhh[1][kt], a1lh, 0, 0, 0);
        }
      }
    }

    // ---- layer0 H MFMAs (after its B2) ----
    if (layer == 0 && s > 1) {
#pragma unroll
      for (int kt = 0; kt < 4; ++kt) {
        int k8 = kq * 16 + kt * 4 + kg;
        bf16x8 ahi = __builtin_bit_cast(
            bf16x8, *(const i32x4*)(s_Hhi + r16 * 512 + ((k8 ^ (r16 & 7)) << 3)));
        bf16x8 alo = __builtin_bit_cast(
            bf16x8, *(const i32x4*)(s_Hlo + r16 * 512 + ((k8 ^ (r16 & 7)) << 3)));
        a0hh = __builtin_amdgcn_mfma_f32_16x16x32_bf16(ahi, whhh[0][kt], a0hh, 0, 0, 0);
        a0hl = __builtin_amdgcn_mfma_f32_16x16x32_bf16(ahi, whhl[0][kt], a0hl, 0, 0, 0);
        a0lh = __builtin_amdgcn_mfma_f32_16x16x32_bf16(alo, whhh[0][kt], a0lh, 0, 0, 0);
        a1hh = __builtin_amdgcn_mfma_f32_16x16x32_bf16(ahi, whhh[1][kt], a1hh, 0, 0, 0);
        a1hl = __builtin_amdgcn_mfma_f32_16x16x32_bf16(ahi, whhl[1][kt], a1hl, 0, 0, 0);
        a1lh = __builtin_amdgcn_mfma_f32_16x16x32_bf16(alo, whhh[1][kt], a1lh, 0, 0, 0);
      }
    }

    // ---- partial-sum write ----
    {
      f32x4 acc0 = (a0i + a0hh) + (a0hl + a0lh);
      f32x4 acc1 = (a1i + a1hh) + (a1hl + a1lh);
#pragma unroll
      for (int j = 0; j < 4; ++j) {
        int m = kg * 4 + j;
        int xr = (m >> 2) & 3;
        int n0i = nh * 32 + 0 * 16 + r16;
        int n1i = nh * 32 + 1 * 16 + r16;
        s_part[kq * 1024 + m * 64 + (n0i ^ (xr << 4))] = acc0[j];
        s_part[kq * 1024 + m * 64 + (n1i ^ (xr << 4))] = acc1[j];
      }
    }
    BAR_LDS();  // last barrier: s_part staged

    // ---- finals: reduce, bias, fast-tanh, pack word (hi|lo4|tag4), publish ----
    {
      int m = tid >> 5, na = (tid & 31) * 2;
      int xr = (m >> 2) & 3;
      float v0 = biasv0, v1 = biasv1;
#pragma unroll
      for (int q2 = 0; q2 < 4; ++q2) {
        const float2* sp =
            (const float2*)(s_part + q2 * 1024 + m * 64 + (na ^ (xr << 4)));
        float2 t = *sp;
        v0 += t.x;
        v1 += t.y;
      }
      v0 = fast_tanh(v0);
      v1 = fast_tanh(v1);
      unsigned short a0 = f2bf(v0), a1 = f2bf(v1);
      unsigned short b0 = f2bf(v0 - bf2f(a0)), b1 = f2bf(v1 - bf2f(a1));
      u32 tag = (u32)(s & 15);
      u32x2 wv;
      wv[0] = ((u32)a0 << 16) | ((u32)b0 & 0xFFF0u) | tag;
      wv[1] = ((u32)a1 << 16) | ((u32)b1 & 0xFFF0u) | tag;
      u32* dst = hsl + (((size_t)layer * 8 + (s & 7)) * 64 + bg * 16 + m) * 512 +
                 c * 64 + na;
      UC_STORE2(dst, wv);
    }
    // fire-and-forget publish; consumers detect via embedded tags
  }
}

__global__ void k_fc(const u32* __restrict__ h1w, const float* __restrict__ fcW,
                     const float* __restrict__ fcb, float* __restrict__ out) {
  int i = threadIdx.x;  // 512 = 64 batch x 8 classes
  int b = i >> 3, cc = i & 7;
  float acc = fcb[cc];
  const u32* ph = h1w + b * 512;
  const float* pw = fcW + cc * 512;
  for (int k = 0; k < 512; k += 4) {
    int4 w4 = *(const int4*)(ph + k);
    float4 wv = *(const float4*)(pw + k);
    acc += (bf2f((unsigned short)((u32)w4.x >> 16)) +
            bf2f((unsigned short)((u32)w4.x & 0xFFF0u))) * wv.x;
    acc += (bf2f((unsigned short)((u32)w4.y >> 16)) +
            bf2f((unsigned short)((u32)w4.y & 0xFFF0u))) * wv.y;
    acc += (bf2f((unsigned short)((u32)w4.z >> 16)) +
            bf2f((unsigned short)((u32)w4.z & 0xFFF0u))) * wv.z;
    acc += (bf2f((unsigned short)((u32)w4.w >> 16)) +
            bf2f((unsigned short)((u32)w4.w & 0xFFF0u))) * wv.w;
  }
  out[b * 8 + cc] = acc;
}

extern "C" void kernel_launch(void* const* d_in, const int* in_sizes, int n_in,
                              void* d_out, int out_size, void* d_ws, size_t ws_size,
                              hipStream_t stream) {
  const int* x = (const int*)d_in[0];
  const float* emb = (const float*)d_in[1];
  const float* Wih0 = (const float*)d_in[2];
  const float* Whh0 = (const float*)d_in[3];
  const float* bih0 = (const float*)d_in[4];
  const float* bhh0 = (const float*)d_in[5];
  const float* Wih1 = (const float*)d_in[6];
  const float* Whh1 = (const float*)d_in[7];
  const float* bih1 = (const float*)d_in[8];
  const float* bhh1 = (const float*)d_in[9];
  const float* fcW = (const float*)d_in[10];
  const float* fcb = (const float*)d_in[11];

  u32* hsl = (u32*)d_ws;  // 2 layers x 8 slots x 64 x 512 u32 = 2 MB

  hipMemsetAsync(hsl, 0, (size_t)2 * 8 * 64 * 512 * 4, stream);
  hipLaunchKernelGGL(k_rnn, dim3(64), dim3(512), 0, stream, x, emb, Wih0, Whh0,
                     bih0, bhh0, Wih1, Whh1, bih1, bhh1, hsl);
  // final h1 = step 512 -> layer1 slot (512&7)==0
  hipLaunchKernelGGL(k_fc, dim3(1), dim3(512), 0, stream,
                     hsl + (size_t)8 * 64 * 512, fcW, fcb, (float*)d_out);
}